// Round 1
// baseline (219.143 us; speedup 1.0000x reference)
//
#include <hip/hip_runtime.h>
#include <math.h>

#define M_ 4
#define A_ 256
#define RBF_ 64
#define F_ 32
#define H_ 32
#define SI_ 32
#define TF_ 128   // 4 tags * F

// ---------------------------------------------------------------------------
// Setup: collapse the two linear Dense layers per tag into one 64x32 map.
// ws layout: Wc[64][128] (k-major, tf = tag*32+f), then bc[128].
// ---------------------------------------------------------------------------
__global__ __launch_bounds__(256) void combine_weights(
    const float* __restrict__ w1_00, const float* __restrict__ b1_00,
    const float* __restrict__ w2_00, const float* __restrict__ b2_00,
    const float* __restrict__ w1_01, const float* __restrict__ b1_01,
    const float* __restrict__ w2_01, const float* __restrict__ b2_01,
    const float* __restrict__ w1_10, const float* __restrict__ b1_10,
    const float* __restrict__ w2_10, const float* __restrict__ b2_10,
    const float* __restrict__ w1_11, const float* __restrict__ b1_11,
    const float* __restrict__ w2_11, const float* __restrict__ b2_11,
    float* __restrict__ ws)
{
  const float* w1s[4] = {w1_00, w1_01, w1_10, w1_11};
  const float* b1s[4] = {b1_00, b1_01, b1_10, b1_11};
  const float* w2s[4] = {w2_00, w2_01, w2_10, w2_11};
  const float* b2s[4] = {b2_00, b2_01, b2_10, b2_11};
  int tid = blockIdx.x * 256 + threadIdx.x;    // 0..8191
  int k   = tid >> 7;
  int tf  = tid & 127;
  int tag = tf >> 5, f = tf & 31;
  const float* w1 = w1s[tag];
  const float* w2 = w2s[tag];
  float s = 0.f;
  for (int h = 0; h < H_; ++h) s += w1[k * H_ + h] * w2[h * F_ + f];
  ws[k * TF_ + tf] = s;
  if (tid < TF_) {
    const float* b1 = b1s[tag];
    const float* b2 = b2s[tag];
    float sb = b2[f];
    for (int h = 0; h < H_; ++h) sb += b1[h] * w2[h * F_ + f];
    ws[64 * TF_ + tf] = sb;
  }
}

__device__ __forceinline__ float sspf(float x) {
  // log(0.5*exp(x)+0.5) = softplus(x) - ln2, numerically stable
  return fmaxf(x, 0.f) + log1pf(expf(-fabsf(x))) - 0.6931471805599453f;
}

// ---------------------------------------------------------------------------
// Main fused kernel: one block per (m,a).
//  - GEMM R[b,tf] = image[m,a,b,:] @ Wc + bc  (register tiled, 4b x 8tf/thread)
//  - 5 equivariant contractions accumulated over b in registers
//  - LDS tree-reduce over the 16 b-thread-groups
//  - self-interaction matmul + equivariant activation epilogue
// Thread map: tb = t>>4 (b groups, rows tb+16i of 64-row chunk),
//             tt = t&15 (tf groups: tf in {4tt..4tt+3} U {64+4tt..67+4tt})
// tt<8  -> tags 00 (out_0x0_0) and 10 (out_1x0_1)
// tt>=8 -> tags 01 (out_0x1_1) and 11 (out_1x1_0 / out_1x1_1)
// ---------------------------------------------------------------------------
__global__ __launch_bounds__(256, 2) void conv_main(
    const float* __restrict__ image, const float* __restrict__ vectors,
    const float* __restrict__ feat0, const float* __restrict__ feat1,
    const float* __restrict__ wc,
    const float* __restrict__ w_si0, const float* __restrict__ w_si1,
    const float* __restrict__ b_act0, const float* __restrict__ b_act1,
    float* __restrict__ out)
{
  struct GemmSh { float W[64 * 132]; float bc[128]; };
  struct RedSh  { float red[16 * 28 * 17]; float cat0[64]; float cat1[288]; };
  union SmemU { GemmSh g; RedSh r; };
  __shared__ SmemU u;
  __shared__ float sA[64 * 68];   // image chunk, rows padded 64->68

  const int t  = threadIdx.x;
  const int m  = blockIdx.x >> 8;
  const int a  = blockIdx.x & 255;
  const int tb = t >> 4;
  const int tt = t & 15;

  // ---- stage combined weights to LDS (rows padded to 132 floats) ----
  #pragma unroll
  for (int i = 0; i < 8; ++i) {
    int f4  = t + 256 * i;               // 0..2047 float4s
    int k   = f4 >> 5;
    int col = (f4 & 31) * 4;
    float4 v = *(const float4*)(wc + k * TF_ + col);
    float* dst = &u.g.W[k * 132 + col];
    dst[0] = v.x; dst[1] = v.y; dst[2] = v.z; dst[3] = v.w;
  }
  if (t < 128) u.g.bc[t] = wc[64 * TF_ + t];
  __syncthreads();

  // bias per accumulator column, into registers (bc area is aliased later)
  float bias[8];
  #pragma unroll
  for (int j = 0; j < 8; ++j) {
    int tf = (j < 4) ? (4 * tt + j) : (64 + 4 * tt + (j - 4));
    bias[j] = u.g.bc[tf];
  }

  // contraction partials (group A: pa=out000, pb=out101; group B: pa=out110,
  // pb=out011, pc=out111)
  float pa[4], pb[12], pc[12];
  #pragma unroll
  for (int q = 0; q < 4; ++q) pa[q] = 0.f;
  #pragma unroll
  for (int e = 0; e < 12; ++e) { pb[e] = 0.f; pc[e] = 0.f; }

  const int f0 = 4 * (tt & 7);

  #pragma unroll 1
  for (int c = 0; c < 4; ++c) {
    __syncthreads();   // protect sA against previous iteration's readers
    // ---- stage image chunk: b in [64c, 64c+64) ----
    const float* imgBase = image + ((m * A_ + a) * A_ + 64 * c) * RBF_;
    #pragma unroll
    for (int i = 0; i < 4; ++i) {
      int f4  = t + 256 * i;             // 0..1023 float4s
      int r   = f4 >> 4;
      int col = (f4 & 15) * 4;
      float4 v = *(const float4*)(imgBase + r * RBF_ + col);
      float* dst = &sA[r * 68 + col];
      dst[0] = v.x; dst[1] = v.y; dst[2] = v.z; dst[3] = v.w;
    }
    __syncthreads();

    // ---- register-tiled GEMM: acc[i][j] = R[b=64c+tb+16i][tf_j] ----
    float acc[4][8];
    #pragma unroll
    for (int i = 0; i < 4; ++i)
      #pragma unroll
      for (int j = 0; j < 8; ++j) acc[i][j] = bias[j];

    #pragma unroll 4
    for (int k = 0; k < 64; k += 4) {
      float av[4][4];
      #pragma unroll
      for (int i = 0; i < 4; ++i) {
        float4 v = *(const float4*)(&sA[(tb + 16 * i) * 68 + k]);
        av[i][0] = v.x; av[i][1] = v.y; av[i][2] = v.z; av[i][3] = v.w;
      }
      #pragma unroll
      for (int kk = 0; kk < 4; ++kk) {
        float4 wl = *(const float4*)(&u.g.W[(k + kk) * 132 + 4 * tt]);
        float4 wh = *(const float4*)(&u.g.W[(k + kk) * 132 + 64 + 4 * tt]);
        float w[8];
        w[0] = wl.x; w[1] = wl.y; w[2] = wl.z; w[3] = wl.w;
        w[4] = wh.x; w[5] = wh.y; w[6] = wh.z; w[7] = wh.w;
        #pragma unroll
        for (int i = 0; i < 4; ++i)
          #pragma unroll
          for (int j = 0; j < 8; ++j)
            acc[i][j] += av[i][kk] * w[j];
      }
    }

    // ---- contractions over this chunk's 4 b's per thread ----
    #pragma unroll
    for (int i = 0; i < 4; ++i) {
      int b = 64 * c + tb + 16 * i;
      float4 v0 = *(const float4*)(feat0 + (m * A_ + b) * F_ + f0);
      float ft0[4] = {v0.x, v0.y, v0.z, v0.w};
      const float* f1p = feat1 + ((m * A_ + b) * F_ + f0) * 3;
      float4 u0 = *(const float4*)(f1p);
      float4 u1 = *(const float4*)(f1p + 4);
      float4 u2 = *(const float4*)(f1p + 8);
      float ft1[12] = {u0.x, u0.y, u0.z, u0.w, u1.x, u1.y, u1.z, u1.w,
                       u2.x, u2.y, u2.z, u2.w};
      if (tt < 8) {
        #pragma unroll
        for (int q = 0; q < 4; ++q) {
          pa[q] += acc[i][q] * ft0[q];                 // out_0x0_0
          float r10 = acc[i][4 + q];                   // out_1x0_1
          pb[q * 3 + 0] += r10 * ft1[q * 3 + 0];
          pb[q * 3 + 1] += r10 * ft1[q * 3 + 1];
          pb[q * 3 + 2] += r10 * ft1[q * 3 + 2];
        }
      } else {
        const float* vp = vectors + ((m * A_ + a) * A_ + b) * 3;
        float vx = vp[0], vy = vp[1], vz = vp[2];
        #pragma unroll
        for (int q = 0; q < 4; ++q) {
          float s = acc[i][q] * ft0[q];                // out_0x1_1
          pb[q * 3 + 0] += vx * s;
          pb[q * 3 + 1] += vy * s;
          pb[q * 3 + 2] += vz * s;
          float r11 = acc[i][4 + q];
          float fx = ft1[q * 3 + 0], fy = ft1[q * 3 + 1], fz = ft1[q * 3 + 2];
          pa[q] += r11 * (vx * fx + vy * fy + vz * fz);        // out_1x1_0
          pc[q * 3 + 0] += r11 * (vy * fz - vz * fy);          // out_1x1_1
          pc[q * 3 + 1] += r11 * (vz * fx - vx * fz);
          pc[q * 3 + 2] += r11 * (vx * fy - vy * fx);
        }
      }
    }
  }

  // ---- reduce partials over the 16 tb groups via LDS ----
  __syncthreads();            // done with u.g (W/bc); repurpose as u.r
  float* red = u.r.red;       // red[(tt*28 + slot)*17 + tb]
  if (tt < 8) {
    #pragma unroll
    for (int q = 0; q < 4; ++q)  red[(tt * 28 + q) * 17 + tb] = pa[q];
    #pragma unroll
    for (int e = 0; e < 12; ++e) red[(tt * 28 + 4 + e) * 17 + tb] = pb[e];
  } else {
    #pragma unroll
    for (int e = 0; e < 12; ++e) red[(tt * 28 + e) * 17 + tb] = pb[e];
    #pragma unroll
    for (int q = 0; q < 4; ++q)  red[(tt * 28 + 12 + q) * 17 + tb] = pa[q];
    #pragma unroll
    for (int e = 0; e < 12; ++e) red[(tt * 28 + 16 + e) * 17 + tb] = pc[e];
  }
  __syncthreads();

  for (int s = t; s < 448; s += 256) {
    int tts = s / 28, sl = s - tts * 28;
    if (tts < 8 && sl >= 16) continue;     // group-A threads use 16 slots only
    float sum = 0.f;
    #pragma unroll
    for (int r2 = 0; r2 < 16; ++r2) sum += red[s * 17 + r2];
    if (tts < 8) {
      int fb = 4 * tts;
      if (sl < 4) u.r.cat0[fb + sl] = sum;                       // out000 -> cat0[0:32)
      else { int e = sl - 4; int q = e / 3, d = e - 3 * q;
             u.r.cat1[(32 + fb + q) * 3 + d] = sum; }            // out101 -> cat1[32:64)
    } else {
      int fb = 4 * (tts - 8);
      if (sl < 12) { int q = sl / 3, d = sl - 3 * q;
                     u.r.cat1[(fb + q) * 3 + d] = sum; }         // out011 -> cat1[0:32)
      else if (sl < 16) u.r.cat0[32 + fb + (sl - 12)] = sum;     // out110 -> cat0[32:64)
      else { int e = sl - 16; int q = e / 3, d = e - 3 * q;
             u.r.cat1[(64 + fb + q) * 3 + d] = sum; }            // out111 -> cat1[64:96)
    }
  }
  __syncthreads();

  // ---- self-interaction + equivariant activation epilogue ----
  const int outBase = (m * A_ + a) * SI_;
  if (t < 32) {
    const float* wr = w_si0 + t * 64;
    float s = 0.f;
    #pragma unroll 8
    for (int f = 0; f < 64; ++f) s += u.r.cat0[f] * wr[f];
    s += b_act0[t];
    out[outBase + t] = sspf(s);
  } else if (t >= 64 && t < 96) {
    int g = t - 64;
    const float* wr = w_si1 + g * 96;
    float s0 = 0.f, s1 = 0.f, s2 = 0.f;
    #pragma unroll 8
    for (int f = 0; f < 96; ++f) {
      float w = wr[f];
      s0 += u.r.cat1[f * 3 + 0] * w;
      s1 += u.r.cat1[f * 3 + 1] * w;
      s2 += u.r.cat1[f * 3 + 2] * w;
    }
    float n2 = s0 * s0 + s1 * s1 + s2 * s2;
    float n1 = sqrtf(fmaxf(n2, 1e-7f));     // norm_with_epsilon, EPS=1e-7
    float a1 = sspf(n1 + b_act1[g]);
    float sc = a1 / n1;
    int ob = M_ * A_ * SI_ + (outBase + g) * 3;   // o0 is 32768 floats
    out[ob + 0] = s0 * sc;
    out[ob + 1] = s1 * sc;
    out[ob + 2] = s2 * sc;
  }
}

extern "C" void kernel_launch(void* const* d_in, const int* in_sizes, int n_in,
                              void* d_out, int out_size, void* d_ws, size_t ws_size,
                              hipStream_t stream) {
  const float* image   = (const float*)d_in[0];
  const float* vectors = (const float*)d_in[1];
  const float* feat0   = (const float*)d_in[2];
  const float* feat1   = (const float*)d_in[3];
  const float* w_si0   = (const float*)d_in[20];
  const float* w_si1   = (const float*)d_in[21];
  const float* b_act0  = (const float*)d_in[22];
  const float* b_act1  = (const float*)d_in[23];
  float* ws  = (float*)d_ws;     // needs 64*128 + 128 floats = 33,280 B
  float* out = (float*)d_out;

  combine_weights<<<32, 256, 0, stream>>>(
      (const float*)d_in[4],  (const float*)d_in[5],
      (const float*)d_in[6],  (const float*)d_in[7],
      (const float*)d_in[8],  (const float*)d_in[9],
      (const float*)d_in[10], (const float*)d_in[11],
      (const float*)d_in[12], (const float*)d_in[13],
      (const float*)d_in[14], (const float*)d_in[15],
      (const float*)d_in[16], (const float*)d_in[17],
      (const float*)d_in[18], (const float*)d_in[19],
      ws);

  conv_main<<<M_ * A_, 256, 0, stream>>>(
      image, vectors, feat0, feat1, ws, w_si0, w_si1, b_act0, b_act1, out);
}